// Round 6
// baseline (447.433 us; speedup 1.0000x reference)
//
#include <hip/hip_runtime.h>
#include <hip/hip_bf16.h>
#include <math.h>

// Problem constants
#define N_CELLS 50000
#define C_CLS   30
#define G_GENES 1000
#define E_EDGES 800000
#define KPAD    1024
#define NREP    4

typedef __attribute__((ext_vector_type(8))) short bf16x8;
typedef __attribute__((ext_vector_type(4))) float f32x4;

// fp32 -> bf16 (RNE), raw ushort payload
__device__ __forceinline__ unsigned f2bf_u(float f) {
    unsigned u = __float_as_uint(f);
    return (u + 0x7fffu + ((u >> 16) & 1u)) >> 16;
}
// packed 2x f32->bf16 via v_cvt_pk_bf16_f32
__device__ __forceinline__ unsigned pack2(float lo, float hi) {
    union { __hip_bfloat162 h; unsigned u; } cv;
    cv.h = __float22bfloat162_rn(make_float2(lo, hi));
    return cv.u;
}
__device__ __forceinline__ float bf2f(unsigned short u) {
    return __uint_as_float(((unsigned)u) << 16);
}

__device__ __forceinline__ float lrelu02(float v) { return v > 0.f ? v : 0.2f * v; }

// pack a pair of float4 (8 consecutive k) into linear and squared bf16x8
__device__ __forceinline__ void pack_pair(const float4& A, const float4& B,
                                          bf16x8* lin, bf16x8* sq) {
    union { unsigned u[4]; bf16x8 v; } ua, u2;
    ua.u[0] = pack2(A.x, A.y); ua.u[1] = pack2(A.z, A.w);
    ua.u[2] = pack2(B.x, B.y); ua.u[3] = pack2(B.z, B.w);
    u2.u[0] = pack2(A.x * A.x, A.y * A.y); u2.u[1] = pack2(A.z * A.z, A.w * A.w);
    u2.u[2] = pack2(B.x * B.x, B.y * B.y); u2.u[3] = pack2(B.z * B.z, B.w * B.w);
    *lin = ua.v; *sq = u2.v;
}

// dot of 8 bf16 pairs packed in one int4
__device__ __forceinline__ float dp4(int4 a, int4 b) {
    const unsigned* ua = (const unsigned*)&a;
    const unsigned* ub = (const unsigned*)&b;
    float s = 0.f;
#pragma unroll
    for (int i = 0; i < 4; i++) {
        float al = __uint_as_float(ua[i] << 16);
        float ah = __uint_as_float(ua[i] & 0xffff0000u);
        float bl = __uint_as_float(ub[i] << 16);
        float bh = __uint_as_float(ub[i] & 0xffff0000u);
        s += al * bl + ah * bh;
    }
    return s;
}

// ---------------------------------------------------------------------------
// K0: pack CoefT (pre-transposed per-lane MFMA B fragments) + Dvec[30];
// zero dn4 accumulators + out[0..1].
// CoefT layout: [kt(16)][nt(5)][ks(2)][lane(64)][8 halfs]:
//   CoefT[((kt*5+nt)*2+ks)*512 + l*8 + j] = B[nt*16+(l&15)][kt*64+ks*32+(l>>4)*8+j]
// so a wave's B-load for (kt,nt,ks) is lane l -> 16B at l*8: 1KB contiguous.
// ---------------------------------------------------------------------------
__global__ void prep_kernel(const float* __restrict__ Mu, const float* __restrict__ Var,
                            const float* __restrict__ Wl, const float* __restrict__ Wr,
                            unsigned short* __restrict__ CoefT, float* __restrict__ Dvec,
                            float* __restrict__ dn4, float* __restrict__ out) {
    const int r = blockIdx.x;
    const int t = threadIdx.x;
    __shared__ float red[256];
    float dacc = 0.f;
    if (r < 80) {
        const int nt  = r >> 4;
        const int l15 = r & 15;
        for (int g = t; g < KPAD; g += 256) {
            float v = 0.f;
            if (g < G_GENES) {
                if (r < 30) {
                    float iv = 1.0f / Var[r * G_GENES + g];
                    float mu = Mu[r * G_GENES + g];
                    v = iv;
                    dacc += mu * mu * iv;
                } else if (r >= 32) {
                    int i = r - 32;
                    if (i < 30)      v = Mu[i * G_GENES + g] / Var[i * G_GENES + g];
                    else if (i < 38) v = Wl[(i - 30) * G_GENES + g];
                    else if (i < 46) v = Wr[(i - 38) * G_GENES + g];
                }
            }
            const int kt = g >> 6;
            const int ks = (g >> 5) & 1;
            const int hi = (g & 31) >> 3;
            const int j  = g & 7;
            const int l  = hi * 16 + l15;
            CoefT[((kt * 5 + nt) * 2 + ks) * 512 + l * 8 + j] = (unsigned short)f2bf_u(v);
        }
    }
    for (int i = blockIdx.x * 256 + t; i < N_CELLS * NREP * 2; i += 80 * 256) dn4[i] = 0.f;
    if (r == 31 && t < 2) out[t] = 0.f;

    if (r < 30) {
        red[t] = dacc;
        __syncthreads();
        for (int s = 128; s > 0; s >>= 1) {
            if (t < s) red[t] += red[t + s];
            __syncthreads();
        }
        if (t == 0) Dvec[r] = red[0];
    }
}

// ---------------------------------------------------------------------------
// K1: MFMA row kernel — K-SPLIT x4, NO LDS staging, NO barriers in the loop.
// Block = 256 thr = 4 waves, all owning the SAME 16 rows; wave w computes
// K in [w*256, w*256+256) (4 K-tiles). B fragments are read from CoefT with
// perfectly coalesced 1KB/wave loads (L2-resident). Partial accumulators are
// combined through a tiny LDS buffer at the end; wave 0 runs the epilogue.
// Grid = 3125 blocks (50000/16 exactly, no tail); 12500 waves = 48.8/CU
// demanded -> ~20 resident (VGPR-capped) -> 4x the TLP of prior rounds.
// ---------------------------------------------------------------------------
__global__ __launch_bounds__(256, 5) void main_rows_kernel(
    const float* __restrict__ X, const float* __restrict__ W,
    const float* __restrict__ S, const float* __restrict__ bl,
    const float* __restrict__ br, const unsigned short* __restrict__ CoefT,
    const float* __restrict__ Dvec,
    float* __restrict__ out,          // [0]=ll, [1]=ce, [2..] = P row-major
    unsigned short* __restrict__ Pb, unsigned short* __restrict__ Lb,
    float* __restrict__ xl, float* __restrict__ xr)
{
    __shared__ __align__(16) float cmb[3][64][21];   // 16.1 KB, pad 21: conflict-free

    const int t    = threadIdx.x;
    const int w    = t >> 6;
    const int l    = t & 63;
    const int l15  = l & 15;
    const int quad = l >> 4;
    const int k0q  = quad * 8;
    const int rowbase = blockIdx.x * 16;             // grid*16 == N exactly
    const float* __restrict__ xrow = X + (size_t)(rowbase + l15) * G_GENES;
    // wave w's CoefT base (K-tiles w*4 .. w*4+3), lane-resolved
    const unsigned short* __restrict__ ctw = CoefT + (size_t)(w * 4 * 5 * 2) * 512 + l * 8;

    f32x4 acc[5];
#pragma unroll
    for (int i = 0; i < 5; i++) acc[i] = (f32x4){0.f, 0.f, 0.f, 0.f};

#pragma unroll
    for (int it = 0; it < 4; ++it) {
        const int kt   = w * 4 + it;
        const int kcol = kt * 64;

        // X loads for this tile (ks=0 pair always in-bounds; ks=1 clamped:
        // kt==15,quad>0 reads cols>=1000 -> clamp addr to 0, coef==0 there)
        float4 a0 = *(const float4*)&xrow[kcol + k0q];
        float4 a1 = *(const float4*)&xrow[kcol + k0q + 4];
        int kb = kcol + 32 + k0q;
        if (kb > 992) kb = 0;
        float4 a2 = *(const float4*)&xrow[kb];
        float4 a3 = *(const float4*)&xrow[kb + 4];

        // ---- ks = 0 ----
        bf16x8 b0 = *(const bf16x8*)&ctw[((it * 5 + 0) * 2 + 0) * 512];
        bf16x8 b1 = *(const bf16x8*)&ctw[((it * 5 + 1) * 2 + 0) * 512];
        bf16x8 b2 = *(const bf16x8*)&ctw[((it * 5 + 2) * 2 + 0) * 512];
        bf16x8 b3 = *(const bf16x8*)&ctw[((it * 5 + 3) * 2 + 0) * 512];
        bf16x8 b4 = *(const bf16x8*)&ctw[((it * 5 + 4) * 2 + 0) * 512];
        bf16x8 va, v2;
        pack_pair(a0, a1, &va, &v2);
        acc[0] = __builtin_amdgcn_mfma_f32_16x16x32_bf16(v2, b0, acc[0], 0, 0, 0);
        acc[1] = __builtin_amdgcn_mfma_f32_16x16x32_bf16(v2, b1, acc[1], 0, 0, 0);
        acc[2] = __builtin_amdgcn_mfma_f32_16x16x32_bf16(va, b2, acc[2], 0, 0, 0);
        acc[3] = __builtin_amdgcn_mfma_f32_16x16x32_bf16(va, b3, acc[3], 0, 0, 0);
        acc[4] = __builtin_amdgcn_mfma_f32_16x16x32_bf16(va, b4, acc[4], 0, 0, 0);

        // ---- ks = 1 ----
        b0 = *(const bf16x8*)&ctw[((it * 5 + 0) * 2 + 1) * 512];
        b1 = *(const bf16x8*)&ctw[((it * 5 + 1) * 2 + 1) * 512];
        b2 = *(const bf16x8*)&ctw[((it * 5 + 2) * 2 + 1) * 512];
        b3 = *(const bf16x8*)&ctw[((it * 5 + 3) * 2 + 1) * 512];
        b4 = *(const bf16x8*)&ctw[((it * 5 + 4) * 2 + 1) * 512];
        pack_pair(a2, a3, &va, &v2);
        acc[0] = __builtin_amdgcn_mfma_f32_16x16x32_bf16(v2, b0, acc[0], 0, 0, 0);
        acc[1] = __builtin_amdgcn_mfma_f32_16x16x32_bf16(v2, b1, acc[1], 0, 0, 0);
        acc[2] = __builtin_amdgcn_mfma_f32_16x16x32_bf16(va, b2, acc[2], 0, 0, 0);
        acc[3] = __builtin_amdgcn_mfma_f32_16x16x32_bf16(va, b3, acc[3], 0, 0, 0);
        acc[4] = __builtin_amdgcn_mfma_f32_16x16x32_bf16(va, b4, acc[4], 0, 0, 0);
    }

    // ---- combine partial K-sums: waves 1..3 deposit, wave 0 reduces ----
    if (w > 0) {
#pragma unroll
        for (int i = 0; i < 5; i++)
#pragma unroll
            for (int r = 0; r < 4; r++) cmb[w - 1][l][i * 4 + r] = acc[i][r];
    }
    __syncthreads();
    if (w != 0) return;
#pragma unroll
    for (int j = 0; j < 3; j++)
#pragma unroll
        for (int i = 0; i < 5; i++)
#pragma unroll
            for (int r = 0; r < 4; r++) acc[i][r] += cmb[j][l][i * 4 + r];

    // Epilogue (wave 0). acc[nt][reg]: packed col = nt*16+l15, row = quad*4+reg.
    const int rbase = rowbase + quad * 4;
    const bool c2ok = (l15 < 14);
    const float d0 = Dvec[l15];
    const float d1 = c2ok ? Dvec[16 + l15] : 0.f;
    float llacc = 0.f;
#pragma unroll
    for (int r = 0; r < 4; r++) {
        const int row = rbase + r;
        float w0 = W[(size_t)row * 30 + l15];
        float w1 = c2ok ? W[(size_t)row * 30 + 16 + l15] : -1e30f;
        float m = fmaxf(w0, w1);
#pragma unroll
        for (int mm = 1; mm < 16; mm <<= 1) m = fmaxf(m, __shfl_xor(m, mm, 64));
        float e0 = __expf(w0 - m);
        float e1 = c2ok ? __expf(w1 - m) : 0.f;
        float s = e0 + e1;
#pragma unroll
        for (int mm = 1; mm < 16; mm <<= 1) s += __shfl_xor(s, mm, 64);
        float inv = 1.0f / s;
        float p0 = e0 * inv, p1 = e1 * inv;
        float Sn = S[row], Sn2 = Sn * Sn;
        float F0 = -0.5f * (acc[0][r] - 2.0f * Sn * acc[2][r] + Sn2 * d0);
        float F1 = -0.5f * (acc[1][r] - 2.0f * Sn * acc[3][r] + Sn2 * d1);
        float lp = p0 * F0 + (c2ok ? p1 * F1 : 0.f);
#pragma unroll
        for (int mm = 1; mm < 16; mm <<= 1) lp += __shfl_xor(lp, mm, 64);
        llacc += lp;

        out[2 + (size_t)row * 30 + l15] = p0;
        float lg0 = __logf(p0 + 1e-8f);
        Pb[(size_t)row * 32 + l15] = (unsigned short)f2bf_u(p0);
        Lb[(size_t)row * 32 + l15] = (unsigned short)f2bf_u(lg0);
        if (c2ok) {
            out[2 + (size_t)row * 30 + 16 + l15] = p1;
            float lg1 = __logf(p1 + 1e-8f);
            Pb[(size_t)row * 32 + 16 + l15] = (unsigned short)f2bf_u(p1);
            Lb[(size_t)row * 32 + 16 + l15] = (unsigned short)f2bf_u(lg1);
        } else {
            Pb[(size_t)row * 32 + 16 + l15] = 0;
            Lb[(size_t)row * 32 + 16 + l15] = 0;
        }
        if (l15 >= 14)                xl[(size_t)row * 8 + (l15 - 14)] = acc[3][r] + bl[l15 - 14];
        else if (l15 < 6)             xl[(size_t)row * 8 + (l15 + 2)]  = acc[4][r] + bl[l15 + 2];
        if (l15 >= 6 && l15 < 14)     xr[(size_t)row * 8 + (l15 - 6)]  = acc[4][r] + br[l15 - 6];
    }
    llacc += __shfl_xor(llacc, 16, 64);
    llacc += __shfl_xor(llacc, 32, 64);
    if (l == 0) atomicAdd(&out[0], llacc * (1.0f / N_CELLS));
}

// ---------------------------------------------------------------------------
// K2: SINGLE edge pass, 4 lanes/edge (coalesced gathers), (p, p*dot) pair
// atomics into NREP replicated same-line slots by dst.
// ---------------------------------------------------------------------------
__global__ __launch_bounds__(256) void edge_pass(
    const int* __restrict__ ei, const float* __restrict__ xl,
    const float* __restrict__ xr, const float* __restrict__ att,
    const unsigned short* __restrict__ Pb, const unsigned short* __restrict__ Lb,
    float* __restrict__ dn4) {
    const int t = threadIdx.x;
    const int g = t >> 2;                     // group in block [0,64)
    const int j = t & 3;
    const int e = blockIdx.x * 64 + g;        // E = 12500*64 exactly
    const int src = ei[e];
    const int dst = ei[E_EDGES + e];

    float2 lv = *(const float2*)&xl[(size_t)src * 8 + j * 2];
    float2 rv = *(const float2*)&xr[(size_t)dst * 8 + j * 2];
    float2 av = *(const float2*)&att[j * 2];
    float ev = lrelu02(lv.x + rv.x) * av.x + lrelu02(lv.y + rv.y) * av.y;
    ev += __shfl_xor(ev, 1, 64);
    ev += __shfl_xor(ev, 2, 64);
    float p = __expf(ev);                     // |ev| ~ O(10): no max-subtraction

    int4 a = *(const int4*)&Pb[(size_t)src * 32 + j * 8];
    int4 b = *(const int4*)&Lb[(size_t)dst * 32 + j * 8];
    float dot = dp4(a, b);
    dot += __shfl_xor(dot, 1, 64);
    dot += __shfl_xor(dot, 2, 64);

    float* base = &dn4[((size_t)(blockIdx.x & (NREP - 1)) * N_CELLS + dst) * 2];
    if (j == 0)      atomicAdd(base, p);
    else if (j == 1) atomicAdd(base + 1, p * dot);
}

// ---------------------------------------------------------------------------
// K3: finalize — fold replicas, ce = -sum numer/denom / N
// ---------------------------------------------------------------------------
__global__ __launch_bounds__(256) void finalize_kernel(const float* __restrict__ dn4,
                                                       float* __restrict__ out) {
    const int t = threadIdx.x;
    const int i = blockIdx.x * 256 + t;
    float c = 0.f;
    if (i < N_CELLS) {
        float d  = (dn4[(size_t)i * 2]     + dn4[((size_t)N_CELLS + i) * 2]) +
                   (dn4[((size_t)2 * N_CELLS + i) * 2] + dn4[((size_t)3 * N_CELLS + i) * 2]);
        float nm = (dn4[(size_t)i * 2 + 1] + dn4[((size_t)N_CELLS + i) * 2 + 1]) +
                   (dn4[((size_t)2 * N_CELLS + i) * 2 + 1] + dn4[((size_t)3 * N_CELLS + i) * 2 + 1]);
        c = nm / (d + 1e-16f);
    }
#pragma unroll
    for (int m = 1; m < 64; m <<= 1) c += __shfl_xor(c, m, 64);
    __shared__ float wsum[4];
    if ((t & 63) == 0) wsum[t >> 6] = c;
    __syncthreads();
    if (t == 0)
        atomicAdd(&out[1], -(wsum[0] + wsum[1] + wsum[2] + wsum[3]) * (1.0f / N_CELLS));
}

// ---------------------------------------------------------------------------
// launch
// ---------------------------------------------------------------------------
extern "C" void kernel_launch(void* const* d_in, const int* in_sizes, int n_in,
                              void* d_out, int out_size, void* d_ws, size_t ws_size,
                              hipStream_t stream) {
    const float* X   = (const float*)d_in[0];
    const float* Mu  = (const float*)d_in[1];
    const float* Var = (const float*)d_in[2];
    const int*   ei  = (const int*)d_in[3];
    const float* W   = (const float*)d_in[4];
    const float* S   = (const float*)d_in[5];
    const float* Wl  = (const float*)d_in[6];
    const float* bl  = (const float*)d_in[7];
    const float* Wr  = (const float*)d_in[8];
    const float* br  = (const float*)d_in[9];
    const float* att = (const float*)d_in[10];

    float* out = (float*)d_out;

    // ws layout (float offsets)
    float* wsf = (float*)d_ws;
    unsigned short* CoefT  = (unsigned short*)wsf;             // 16*5*2*512*8... = 81920 us = 40960 fl
    float* Dvec            = wsf + 40960;                      // 32
    unsigned short* Pb     = (unsigned short*)(wsf + 40992);   // N*32 us = 800000 fl
    unsigned short* Lb     = (unsigned short*)(wsf + 840992);  // N*32 us
    float* xl              = wsf + 1640992;                    // N*8
    float* xr              = wsf + 2040992;                    // N*8
    float* dn4             = wsf + 2440992;                    // NREP*N*2 = 400000

    prep_kernel<<<80, 256, 0, stream>>>(Mu, Var, Wl, Wr, CoefT, Dvec, dn4, out);
    main_rows_kernel<<<N_CELLS / 16, 256, 0, stream>>>(
        X, W, S, bl, br, CoefT, Dvec, out, Pb, Lb, xl, xr);
    edge_pass<<<E_EDGES / 64, 256, 0, stream>>>(ei, xl, xr, att, Pb, Lb, dn4);
    finalize_kernel<<<(N_CELLS + 255) / 256, 256, 0, stream>>>(dn4, out);
}

// Round 7
// 437.172 us; speedup vs baseline: 1.0235x; 1.0235x over previous
//
#include <hip/hip_runtime.h>
#include <hip/hip_bf16.h>
#include <math.h>

// Problem constants
#define N_CELLS 50000
#define C_CLS   30
#define G_GENES 1000
#define E_EDGES 800000
#define KPAD    1024
#define NREP    4

typedef __attribute__((ext_vector_type(8))) short bf16x8;
typedef __attribute__((ext_vector_type(4))) float f32x4;

// fp32 -> bf16 (RNE), raw ushort payload
__device__ __forceinline__ unsigned f2bf_u(float f) {
    unsigned u = __float_as_uint(f);
    return (u + 0x7fffu + ((u >> 16) & 1u)) >> 16;
}
// packed 2x f32->bf16 via v_cvt_pk_bf16_f32
__device__ __forceinline__ unsigned pack2(float lo, float hi) {
    union { __hip_bfloat162 h; unsigned u; } cv;
    cv.h = __float22bfloat162_rn(make_float2(lo, hi));
    return cv.u;
}
__device__ __forceinline__ float bf2f(unsigned short u) {
    return __uint_as_float(((unsigned)u) << 16);
}

__device__ __forceinline__ float lrelu02(float v) { return v > 0.f ? v : 0.2f * v; }

// pack a pair of float4 (8 consecutive k) into linear and squared bf16x8
__device__ __forceinline__ void pack_pair(const float4& A, const float4& B,
                                          bf16x8* lin, bf16x8* sq) {
    union { unsigned u[4]; bf16x8 v; } ua, u2;
    ua.u[0] = pack2(A.x, A.y); ua.u[1] = pack2(A.z, A.w);
    ua.u[2] = pack2(B.x, B.y); ua.u[3] = pack2(B.z, B.w);
    u2.u[0] = pack2(A.x * A.x, A.y * A.y); u2.u[1] = pack2(A.z * A.z, A.w * A.w);
    u2.u[2] = pack2(B.x * B.x, B.y * B.y); u2.u[3] = pack2(B.z * B.z, B.w * B.w);
    *lin = ua.v; *sq = u2.v;
}

// dot of 8 bf16 pairs packed in one int4
__device__ __forceinline__ float dp4(int4 a, int4 b) {
    const unsigned* ua = (const unsigned*)&a;
    const unsigned* ub = (const unsigned*)&b;
    float s = 0.f;
#pragma unroll
    for (int i = 0; i < 4; i++) {
        float al = __uint_as_float(ua[i] << 16);
        float ah = __uint_as_float(ua[i] & 0xffff0000u);
        float bl = __uint_as_float(ub[i] << 16);
        float bh = __uint_as_float(ub[i] & 0xffff0000u);
        s += al * bl + ah * bh;
    }
    return s;
}

// ---------------------------------------------------------------------------
// K0: pack CoefT (pre-transposed per-lane MFMA B fragments) + Dvec[30];
// zero dn4 accumulators + out[0..1].
// CoefT layout: [kt(16)][nt(5)][ks(2)][lane(64)][8 halfs]:
//   CoefT[((kt*5+nt)*2+ks)*512 + l*8 + j] = B[nt*16+(l&15)][kt*64+ks*32+(l>>4)*8+j]
// so a wave's B-load for (kt,nt,ks) is lane l -> 16B at l*8: 1KB contiguous.
// ---------------------------------------------------------------------------
__global__ void prep_kernel(const float* __restrict__ Mu, const float* __restrict__ Var,
                            const float* __restrict__ Wl, const float* __restrict__ Wr,
                            unsigned short* __restrict__ CoefT, float* __restrict__ Dvec,
                            float* __restrict__ dn4, float* __restrict__ out) {
    const int r = blockIdx.x;
    const int t = threadIdx.x;
    __shared__ float red[256];
    float dacc = 0.f;
    if (r < 80) {
        const int nt  = r >> 4;
        const int l15 = r & 15;
        for (int g = t; g < KPAD; g += 256) {
            float v = 0.f;
            if (g < G_GENES) {
                if (r < 30) {
                    float iv = 1.0f / Var[r * G_GENES + g];
                    float mu = Mu[r * G_GENES + g];
                    v = iv;
                    dacc += mu * mu * iv;
                } else if (r >= 32) {
                    int i = r - 32;
                    if (i < 30)      v = Mu[i * G_GENES + g] / Var[i * G_GENES + g];
                    else if (i < 38) v = Wl[(i - 30) * G_GENES + g];
                    else if (i < 46) v = Wr[(i - 38) * G_GENES + g];
                }
            }
            const int kt = g >> 6;
            const int ks = (g >> 5) & 1;
            const int hi = (g & 31) >> 3;
            const int j  = g & 7;
            const int l  = hi * 16 + l15;
            CoefT[((kt * 5 + nt) * 2 + ks) * 512 + l * 8 + j] = (unsigned short)f2bf_u(v);
        }
    }
    for (int i = blockIdx.x * 256 + t; i < N_CELLS * NREP * 2; i += 80 * 256) dn4[i] = 0.f;
    if (r == 31 && t < 2) out[t] = 0.f;

    if (r < 30) {
        red[t] = dacc;
        __syncthreads();
        for (int s = 128; s > 0; s >>= 1) {
            if (t < s) red[t] += red[t + s];
            __syncthreads();
        }
        if (t == 0) Dvec[r] = red[0];
    }
}

// ---------------------------------------------------------------------------
// K1: MFMA row kernel — K-SPLIT x4, barrier-free, X BURST PREFETCH.
// Block = 256 thr = 4 waves owning the SAME 16 rows; wave w computes
// K in [w*256, w*256+256). ALL 16 X float4 loads per lane are issued
// UP FRONT into dedicated registers (64 VGPRs) so 16 long-latency HBM
// loads are in flight per wave; B fragments (L2-resident CoefT, coalesced
// 1KB/wave) are loaded per tile. launch_bounds(256,3): VGPR cap 170 so the
// compiler does NOT serialize the burst (round-6 failure: 48 VGPRs -> 2
// loads in flight -> 1.15 TB/s).
// ---------------------------------------------------------------------------
__global__ __launch_bounds__(256, 3) void main_rows_kernel(
    const float* __restrict__ X, const float* __restrict__ W,
    const float* __restrict__ S, const float* __restrict__ bl,
    const float* __restrict__ br, const unsigned short* __restrict__ CoefT,
    const float* __restrict__ Dvec,
    float* __restrict__ out,          // [0]=ll, [1]=ce, [2..] = P row-major
    unsigned short* __restrict__ Pb, unsigned short* __restrict__ Lb,
    float* __restrict__ xl, float* __restrict__ xr)
{
    __shared__ __align__(16) float cmb[3][64][21];   // 16.1 KB, pad 21: conflict-free

    const int t    = threadIdx.x;
    const int w    = t >> 6;
    const int l    = t & 63;
    const int l15  = l & 15;
    const int quad = l >> 4;
    const int k0q  = quad * 8;
    const int rowbase = blockIdx.x * 16;             // grid*16 == N exactly
    const float* __restrict__ xrow = X + (size_t)(rowbase + l15) * G_GENES;
    // wave w's CoefT base (K-tiles w*4 .. w*4+3), lane-resolved
    const unsigned short* __restrict__ ctw = CoefT + (size_t)(w * 4 * 5 * 2) * 512 + l * 8;

    f32x4 acc[5];
#pragma unroll
    for (int i = 0; i < 5; i++) acc[i] = (f32x4){0.f, 0.f, 0.f, 0.f};

    // ---- X BURST: issue all 16 float4 loads (4 tiles x 4 frags) up front ----
    float4 xv[16];
#pragma unroll
    for (int it = 0; it < 4; ++it) {
        const int kcol = (w * 4 + it) * 64;
        xv[it * 4 + 0] = *(const float4*)&xrow[kcol + k0q];
        xv[it * 4 + 1] = *(const float4*)&xrow[kcol + k0q + 4];
        int kb = kcol + 32 + k0q;                    // kt==15,quad>0: cols>=1000
        if (kb > 992) kb = 0;                        // clamp; coef==0 kills garbage
        xv[it * 4 + 2] = *(const float4*)&xrow[kb];
        xv[it * 4 + 3] = *(const float4*)&xrow[kb + 4];
    }

#pragma unroll
    for (int it = 0; it < 4; ++it) {
        // ---- ks = 0 ----
        bf16x8 b0 = *(const bf16x8*)&ctw[((it * 5 + 0) * 2 + 0) * 512];
        bf16x8 b1 = *(const bf16x8*)&ctw[((it * 5 + 1) * 2 + 0) * 512];
        bf16x8 b2 = *(const bf16x8*)&ctw[((it * 5 + 2) * 2 + 0) * 512];
        bf16x8 b3 = *(const bf16x8*)&ctw[((it * 5 + 3) * 2 + 0) * 512];
        bf16x8 b4 = *(const bf16x8*)&ctw[((it * 5 + 4) * 2 + 0) * 512];
        bf16x8 va, v2;
        pack_pair(xv[it * 4 + 0], xv[it * 4 + 1], &va, &v2);
        acc[0] = __builtin_amdgcn_mfma_f32_16x16x32_bf16(v2, b0, acc[0], 0, 0, 0);
        acc[1] = __builtin_amdgcn_mfma_f32_16x16x32_bf16(v2, b1, acc[1], 0, 0, 0);
        acc[2] = __builtin_amdgcn_mfma_f32_16x16x32_bf16(va, b2, acc[2], 0, 0, 0);
        acc[3] = __builtin_amdgcn_mfma_f32_16x16x32_bf16(va, b3, acc[3], 0, 0, 0);
        acc[4] = __builtin_amdgcn_mfma_f32_16x16x32_bf16(va, b4, acc[4], 0, 0, 0);

        // ---- ks = 1 ----
        b0 = *(const bf16x8*)&ctw[((it * 5 + 0) * 2 + 1) * 512];
        b1 = *(const bf16x8*)&ctw[((it * 5 + 1) * 2 + 1) * 512];
        b2 = *(const bf16x8*)&ctw[((it * 5 + 2) * 2 + 1) * 512];
        b3 = *(const bf16x8*)&ctw[((it * 5 + 3) * 2 + 1) * 512];
        b4 = *(const bf16x8*)&ctw[((it * 5 + 4) * 2 + 1) * 512];
        pack_pair(xv[it * 4 + 2], xv[it * 4 + 3], &va, &v2);
        acc[0] = __builtin_amdgcn_mfma_f32_16x16x32_bf16(v2, b0, acc[0], 0, 0, 0);
        acc[1] = __builtin_amdgcn_mfma_f32_16x16x32_bf16(v2, b1, acc[1], 0, 0, 0);
        acc[2] = __builtin_amdgcn_mfma_f32_16x16x32_bf16(va, b2, acc[2], 0, 0, 0);
        acc[3] = __builtin_amdgcn_mfma_f32_16x16x32_bf16(va, b3, acc[3], 0, 0, 0);
        acc[4] = __builtin_amdgcn_mfma_f32_16x16x32_bf16(va, b4, acc[4], 0, 0, 0);
    }

    // ---- combine partial K-sums: waves 1..3 deposit, wave 0 reduces ----
    if (w > 0) {
#pragma unroll
        for (int i = 0; i < 5; i++)
#pragma unroll
            for (int r = 0; r < 4; r++) cmb[w - 1][l][i * 4 + r] = acc[i][r];
    }
    __syncthreads();
    if (w != 0) return;
#pragma unroll
    for (int j = 0; j < 3; j++)
#pragma unroll
        for (int i = 0; i < 5; i++)
#pragma unroll
            for (int r = 0; r < 4; r++) acc[i][r] += cmb[j][l][i * 4 + r];

    // Epilogue (wave 0). acc[nt][reg]: packed col = nt*16+l15, row = quad*4+reg.
    const int rbase = rowbase + quad * 4;
    const bool c2ok = (l15 < 14);
    const float d0 = Dvec[l15];
    const float d1 = c2ok ? Dvec[16 + l15] : 0.f;
    float llacc = 0.f;
#pragma unroll
    for (int r = 0; r < 4; r++) {
        const int row = rbase + r;
        float w0 = W[(size_t)row * 30 + l15];
        float w1 = c2ok ? W[(size_t)row * 30 + 16 + l15] : -1e30f;
        float m = fmaxf(w0, w1);
#pragma unroll
        for (int mm = 1; mm < 16; mm <<= 1) m = fmaxf(m, __shfl_xor(m, mm, 64));
        float e0 = __expf(w0 - m);
        float e1 = c2ok ? __expf(w1 - m) : 0.f;
        float s = e0 + e1;
#pragma unroll
        for (int mm = 1; mm < 16; mm <<= 1) s += __shfl_xor(s, mm, 64);
        float inv = 1.0f / s;
        float p0 = e0 * inv, p1 = e1 * inv;
        float Sn = S[row], Sn2 = Sn * Sn;
        float F0 = -0.5f * (acc[0][r] - 2.0f * Sn * acc[2][r] + Sn2 * d0);
        float F1 = -0.5f * (acc[1][r] - 2.0f * Sn * acc[3][r] + Sn2 * d1);
        float lp = p0 * F0 + (c2ok ? p1 * F1 : 0.f);
#pragma unroll
        for (int mm = 1; mm < 16; mm <<= 1) lp += __shfl_xor(lp, mm, 64);
        llacc += lp;

        out[2 + (size_t)row * 30 + l15] = p0;
        float lg0 = __logf(p0 + 1e-8f);
        Pb[(size_t)row * 32 + l15] = (unsigned short)f2bf_u(p0);
        Lb[(size_t)row * 32 + l15] = (unsigned short)f2bf_u(lg0);
        if (c2ok) {
            out[2 + (size_t)row * 30 + 16 + l15] = p1;
            float lg1 = __logf(p1 + 1e-8f);
            Pb[(size_t)row * 32 + 16 + l15] = (unsigned short)f2bf_u(p1);
            Lb[(size_t)row * 32 + 16 + l15] = (unsigned short)f2bf_u(lg1);
        } else {
            Pb[(size_t)row * 32 + 16 + l15] = 0;
            Lb[(size_t)row * 32 + 16 + l15] = 0;
        }
        if (l15 >= 14)                xl[(size_t)row * 8 + (l15 - 14)] = acc[3][r] + bl[l15 - 14];
        else if (l15 < 6)             xl[(size_t)row * 8 + (l15 + 2)]  = acc[4][r] + bl[l15 + 2];
        if (l15 >= 6 && l15 < 14)     xr[(size_t)row * 8 + (l15 - 6)]  = acc[4][r] + br[l15 - 6];
    }
    llacc += __shfl_xor(llacc, 16, 64);
    llacc += __shfl_xor(llacc, 32, 64);
    if (l == 0) atomicAdd(&out[0], llacc * (1.0f / N_CELLS));
}

// ---------------------------------------------------------------------------
// K2: SINGLE edge pass, 4 lanes/edge (coalesced gathers), (p, p*dot) pair
// atomics into NREP replicated same-line slots by dst.
// ---------------------------------------------------------------------------
__global__ __launch_bounds__(256) void edge_pass(
    const int* __restrict__ ei, const float* __restrict__ xl,
    const float* __restrict__ xr, const float* __restrict__ att,
    const unsigned short* __restrict__ Pb, const unsigned short* __restrict__ Lb,
    float* __restrict__ dn4) {
    const int t = threadIdx.x;
    const int g = t >> 2;                     // group in block [0,64)
    const int j = t & 3;
    const int e = blockIdx.x * 64 + g;        // E = 12500*64 exactly
    const int src = ei[e];
    const int dst = ei[E_EDGES + e];

    float2 lv = *(const float2*)&xl[(size_t)src * 8 + j * 2];
    float2 rv = *(const float2*)&xr[(size_t)dst * 8 + j * 2];
    float2 av = *(const float2*)&att[j * 2];
    float ev = lrelu02(lv.x + rv.x) * av.x + lrelu02(lv.y + rv.y) * av.y;
    ev += __shfl_xor(ev, 1, 64);
    ev += __shfl_xor(ev, 2, 64);
    float p = __expf(ev);                     // |ev| ~ O(10): no max-subtraction

    int4 a = *(const int4*)&Pb[(size_t)src * 32 + j * 8];
    int4 b = *(const int4*)&Lb[(size_t)dst * 32 + j * 8];
    float dot = dp4(a, b);
    dot += __shfl_xor(dot, 1, 64);
    dot += __shfl_xor(dot, 2, 64);

    float* base = &dn4[((size_t)(blockIdx.x & (NREP - 1)) * N_CELLS + dst) * 2];
    if (j == 0)      atomicAdd(base, p);
    else if (j == 1) atomicAdd(base + 1, p * dot);
}

// ---------------------------------------------------------------------------
// K3: finalize — fold replicas, ce = -sum numer/denom / N
// ---------------------------------------------------------------------------
__global__ __launch_bounds__(256) void finalize_kernel(const float* __restrict__ dn4,
                                                       float* __restrict__ out) {
    const int t = threadIdx.x;
    const int i = blockIdx.x * 256 + t;
    float c = 0.f;
    if (i < N_CELLS) {
        float d  = (dn4[(size_t)i * 2]     + dn4[((size_t)N_CELLS + i) * 2]) +
                   (dn4[((size_t)2 * N_CELLS + i) * 2] + dn4[((size_t)3 * N_CELLS + i) * 2]);
        float nm = (dn4[(size_t)i * 2 + 1] + dn4[((size_t)N_CELLS + i) * 2 + 1]) +
                   (dn4[((size_t)2 * N_CELLS + i) * 2 + 1] + dn4[((size_t)3 * N_CELLS + i) * 2 + 1]);
        c = nm / (d + 1e-16f);
    }
#pragma unroll
    for (int m = 1; m < 64; m <<= 1) c += __shfl_xor(c, m, 64);
    __shared__ float wsum[4];
    if ((t & 63) == 0) wsum[t >> 6] = c;
    __syncthreads();
    if (t == 0)
        atomicAdd(&out[1], -(wsum[0] + wsum[1] + wsum[2] + wsum[3]) * (1.0f / N_CELLS));
}

// ---------------------------------------------------------------------------
// launch
// ---------------------------------------------------------------------------
extern "C" void kernel_launch(void* const* d_in, const int* in_sizes, int n_in,
                              void* d_out, int out_size, void* d_ws, size_t ws_size,
                              hipStream_t stream) {
    const float* X   = (const float*)d_in[0];
    const float* Mu  = (const float*)d_in[1];
    const float* Var = (const float*)d_in[2];
    const int*   ei  = (const int*)d_in[3];
    const float* W   = (const float*)d_in[4];
    const float* S   = (const float*)d_in[5];
    const float* Wl  = (const float*)d_in[6];
    const float* bl  = (const float*)d_in[7];
    const float* Wr  = (const float*)d_in[8];
    const float* br  = (const float*)d_in[9];
    const float* att = (const float*)d_in[10];

    float* out = (float*)d_out;

    // ws layout (float offsets)
    float* wsf = (float*)d_ws;
    unsigned short* CoefT  = (unsigned short*)wsf;             // 160 KB = 40960 fl
    float* Dvec            = wsf + 40960;                      // 32
    unsigned short* Pb     = (unsigned short*)(wsf + 40992);   // N*32 us = 800000 fl
    unsigned short* Lb     = (unsigned short*)(wsf + 840992);  // N*32 us
    float* xl              = wsf + 1640992;                    // N*8
    float* xr              = wsf + 2040992;                    // N*8
    float* dn4             = wsf + 2440992;                    // NREP*N*2 = 400000

    prep_kernel<<<80, 256, 0, stream>>>(Mu, Var, Wl, Wr, CoefT, Dvec, dn4, out);
    main_rows_kernel<<<N_CELLS / 16, 256, 0, stream>>>(
        X, W, S, bl, br, CoefT, Dvec, out, Pb, Lb, xl, xr);
    edge_pass<<<E_EDGES / 64, 256, 0, stream>>>(ei, xl, xr, att, Pb, Lb, dn4);
    finalize_kernel<<<(N_CELLS + 255) / 256, 256, 0, stream>>>(dn4, out);
}

// Round 8
// 418.792 us; speedup vs baseline: 1.0684x; 1.0439x over previous
//
#include <hip/hip_runtime.h>
#include <hip/hip_bf16.h>
#include <math.h>

// Problem constants
#define N_CELLS 50000
#define C_CLS   30
#define G_GENES 1000
#define E_EDGES 800000
#define KPAD    1024
#define NREP    4

typedef __attribute__((ext_vector_type(8))) short bf16x8;
typedef __attribute__((ext_vector_type(4))) float f32x4;

// fp32 -> bf16 (RNE), raw ushort payload
__device__ __forceinline__ unsigned f2bf_u(float f) {
    unsigned u = __float_as_uint(f);
    return (u + 0x7fffu + ((u >> 16) & 1u)) >> 16;
}
// packed 2x f32->bf16 via v_cvt_pk_bf16_f32
__device__ __forceinline__ unsigned pack2(float lo, float hi) {
    union { __hip_bfloat162 h; unsigned u; } cv;
    cv.h = __float22bfloat162_rn(make_float2(lo, hi));
    return cv.u;
}
__device__ __forceinline__ float bf2f(unsigned short u) {
    return __uint_as_float(((unsigned)u) << 16);
}

__device__ __forceinline__ float lrelu02(float v) { return v > 0.f ? v : 0.2f * v; }

// pack a pair of float4 (8 consecutive k) into linear and squared bf16x8
__device__ __forceinline__ void pack_pair(const float4& A, const float4& B,
                                          bf16x8* lin, bf16x8* sq) {
    union { unsigned u[4]; bf16x8 v; } ua, u2;
    ua.u[0] = pack2(A.x, A.y); ua.u[1] = pack2(A.z, A.w);
    ua.u[2] = pack2(B.x, B.y); ua.u[3] = pack2(B.z, B.w);
    u2.u[0] = pack2(A.x * A.x, A.y * A.y); u2.u[1] = pack2(A.z * A.z, A.w * A.w);
    u2.u[2] = pack2(B.x * B.x, B.y * B.y); u2.u[3] = pack2(B.z * B.z, B.w * B.w);
    *lin = ua.v; *sq = u2.v;
}

// dot of 8 bf16 pairs packed in one int4
__device__ __forceinline__ float dp4(int4 a, int4 b) {
    const unsigned* ua = (const unsigned*)&a;
    const unsigned* ub = (const unsigned*)&b;
    float s = 0.f;
#pragma unroll
    for (int i = 0; i < 4; i++) {
        float al = __uint_as_float(ua[i] << 16);
        float ah = __uint_as_float(ua[i] & 0xffff0000u);
        float bl = __uint_as_float(ub[i] << 16);
        float bh = __uint_as_float(ub[i] & 0xffff0000u);
        s += al * bl + ah * bh;
    }
    return s;
}

// ---------------------------------------------------------------------------
// K0: pack CoefT (pre-transposed per-lane MFMA B fragments) + Dvec[30];
// zero dn4 accumulators + out[0..1]. Grid 400: blocks 0-79 build CoefT/Dvec,
// all 400 share the dn4 zeroing (was 0.3 blocks/CU = pure latency).
// CoefT layout: [kt(16)][nt(5)][ks(2)][lane(64)][8 halfs]:
//   CoefT[((kt*5+nt)*2+ks)*512 + l*8 + j] = B[nt*16+(l&15)][kt*64+ks*32+(l>>4)*8+j]
// ---------------------------------------------------------------------------
__global__ void prep_kernel(const float* __restrict__ Mu, const float* __restrict__ Var,
                            const float* __restrict__ Wl, const float* __restrict__ Wr,
                            unsigned short* __restrict__ CoefT, float* __restrict__ Dvec,
                            float* __restrict__ dn4, float* __restrict__ out) {
    const int r = blockIdx.x;
    const int t = threadIdx.x;
    __shared__ float red[256];
    float dacc = 0.f;
    if (r < 80) {
        const int nt  = r >> 4;
        const int l15 = r & 15;
        for (int g = t; g < KPAD; g += 256) {
            float v = 0.f;
            if (g < G_GENES) {
                if (r < 30) {
                    float iv = 1.0f / Var[r * G_GENES + g];
                    float mu = Mu[r * G_GENES + g];
                    v = iv;
                    dacc += mu * mu * iv;
                } else if (r >= 32) {
                    int i = r - 32;
                    if (i < 30)      v = Mu[i * G_GENES + g] / Var[i * G_GENES + g];
                    else if (i < 38) v = Wl[(i - 30) * G_GENES + g];
                    else if (i < 46) v = Wr[(i - 38) * G_GENES + g];
                }
            }
            const int kt = g >> 6;
            const int ks = (g >> 5) & 1;
            const int hi = (g & 31) >> 3;
            const int j  = g & 7;
            const int l  = hi * 16 + l15;
            CoefT[((kt * 5 + nt) * 2 + ks) * 512 + l * 8 + j] = (unsigned short)f2bf_u(v);
        }
    }
    for (int i = blockIdx.x * 256 + t; i < N_CELLS * NREP * 2; i += 400 * 256) dn4[i] = 0.f;
    if (r == 100 && t < 2) out[t] = 0.f;

    if (r < 30) {
        red[t] = dacc;
        __syncthreads();
        for (int s = 128; s > 0; s >>= 1) {
            if (t < s) red[t] += red[t + s];
            __syncthreads();
        }
        if (t == 0) Dvec[r] = red[0];
    }
}

// ---------------------------------------------------------------------------
// K1: MFMA row kernel — K-SPLIT x4, barrier-free, X BURST pinned by
// sched_barrier(0). Round-7 failure mode: the compiler SANK the 16-load
// burst back into the loop (VGPR_Count=60 < the 64 the burst needs), giving
// ~2 loads in flight/wave and 1.09 TB/s. The compile-time fence makes all
// 16 destinations live across it -> all 16 loads issued before any MFMA.
// launch_bounds(256,2): VGPR cap 256 so hoisted B-loads don't reserialize.
// ---------------------------------------------------------------------------
__global__ __launch_bounds__(256, 2) void main_rows_kernel(
    const float* __restrict__ X, const float* __restrict__ W,
    const float* __restrict__ S, const float* __restrict__ bl,
    const float* __restrict__ br, const unsigned short* __restrict__ CoefT,
    const float* __restrict__ Dvec,
    float* __restrict__ out,          // [0]=ll, [1]=ce, [2..] = P row-major
    unsigned short* __restrict__ Pb, unsigned short* __restrict__ Lb,
    float* __restrict__ xl, float* __restrict__ xr)
{
    __shared__ __align__(16) float cmb[3][64][21];   // 16.1 KB, pad 21: conflict-free

    const int t    = threadIdx.x;
    const int w    = t >> 6;
    const int l    = t & 63;
    const int l15  = l & 15;
    const int quad = l >> 4;
    const int k0q  = quad * 8;
    const int rowbase = blockIdx.x * 16;             // grid*16 == N exactly
    const float* __restrict__ xrow = X + (size_t)(rowbase + l15) * G_GENES;
    // wave w's CoefT base (K-tiles w*4 .. w*4+3), lane-resolved
    const unsigned short* __restrict__ ctw = CoefT + (size_t)(w * 4 * 5 * 2) * 512 + l * 8;

    f32x4 acc[5];
#pragma unroll
    for (int i = 0; i < 5; i++) acc[i] = (f32x4){0.f, 0.f, 0.f, 0.f};

    // ---- X BURST: issue all 16 float4 loads (4 tiles x 4 frags) ----
    float4 xv[16];
#pragma unroll
    for (int it = 0; it < 4; ++it) {
        const int kcol = (w * 4 + it) * 64;
        xv[it * 4 + 0] = *(const float4*)&xrow[kcol + k0q];
        xv[it * 4 + 1] = *(const float4*)&xrow[kcol + k0q + 4];
        int kb = kcol + 32 + k0q;                    // kt==15,quad>0: cols>=1000
        if (kb > 992) kb = 0;                        // clamp; coef==0 kills garbage
        xv[it * 4 + 2] = *(const float4*)&xrow[kb];
        xv[it * 4 + 3] = *(const float4*)&xrow[kb + 4];
    }
    // Compile-time fence: nothing crosses. All 16 loads are issued and their
    // 64 destination VGPRs are live here -> 16 loads in flight per wave.
    __builtin_amdgcn_sched_barrier(0);

#pragma unroll
    for (int it = 0; it < 4; ++it) {
        // ---- ks = 0 ----
        bf16x8 b0 = *(const bf16x8*)&ctw[((it * 5 + 0) * 2 + 0) * 512];
        bf16x8 b1 = *(const bf16x8*)&ctw[((it * 5 + 1) * 2 + 0) * 512];
        bf16x8 b2 = *(const bf16x8*)&ctw[((it * 5 + 2) * 2 + 0) * 512];
        bf16x8 b3 = *(const bf16x8*)&ctw[((it * 5 + 3) * 2 + 0) * 512];
        bf16x8 b4 = *(const bf16x8*)&ctw[((it * 5 + 4) * 2 + 0) * 512];
        bf16x8 va, v2;
        pack_pair(xv[it * 4 + 0], xv[it * 4 + 1], &va, &v2);
        acc[0] = __builtin_amdgcn_mfma_f32_16x16x32_bf16(v2, b0, acc[0], 0, 0, 0);
        acc[1] = __builtin_amdgcn_mfma_f32_16x16x32_bf16(v2, b1, acc[1], 0, 0, 0);
        acc[2] = __builtin_amdgcn_mfma_f32_16x16x32_bf16(va, b2, acc[2], 0, 0, 0);
        acc[3] = __builtin_amdgcn_mfma_f32_16x16x32_bf16(va, b3, acc[3], 0, 0, 0);
        acc[4] = __builtin_amdgcn_mfma_f32_16x16x32_bf16(va, b4, acc[4], 0, 0, 0);

        // ---- ks = 1 ----
        b0 = *(const bf16x8*)&ctw[((it * 5 + 0) * 2 + 1) * 512];
        b1 = *(const bf16x8*)&ctw[((it * 5 + 1) * 2 + 1) * 512];
        b2 = *(const bf16x8*)&ctw[((it * 5 + 2) * 2 + 1) * 512];
        b3 = *(const bf16x8*)&ctw[((it * 5 + 3) * 2 + 1) * 512];
        b4 = *(const bf16x8*)&ctw[((it * 5 + 4) * 2 + 1) * 512];
        pack_pair(xv[it * 4 + 2], xv[it * 4 + 3], &va, &v2);
        acc[0] = __builtin_amdgcn_mfma_f32_16x16x32_bf16(v2, b0, acc[0], 0, 0, 0);
        acc[1] = __builtin_amdgcn_mfma_f32_16x16x32_bf16(v2, b1, acc[1], 0, 0, 0);
        acc[2] = __builtin_amdgcn_mfma_f32_16x16x32_bf16(va, b2, acc[2], 0, 0, 0);
        acc[3] = __builtin_amdgcn_mfma_f32_16x16x32_bf16(va, b3, acc[3], 0, 0, 0);
        acc[4] = __builtin_amdgcn_mfma_f32_16x16x32_bf16(va, b4, acc[4], 0, 0, 0);
    }

    // ---- combine partial K-sums: waves 1..3 deposit, wave 0 reduces ----
    if (w > 0) {
#pragma unroll
        for (int i = 0; i < 5; i++)
#pragma unroll
            for (int r = 0; r < 4; r++) cmb[w - 1][l][i * 4 + r] = acc[i][r];
    }
    __syncthreads();
    if (w != 0) return;
#pragma unroll
    for (int j = 0; j < 3; j++)
#pragma unroll
        for (int i = 0; i < 5; i++)
#pragma unroll
            for (int r = 0; r < 4; r++) acc[i][r] += cmb[j][l][i * 4 + r];

    // Epilogue (wave 0). acc[nt][reg]: packed col = nt*16+l15, row = quad*4+reg.
    const int rbase = rowbase + quad * 4;
    const bool c2ok = (l15 < 14);
    const float d0 = Dvec[l15];
    const float d1 = c2ok ? Dvec[16 + l15] : 0.f;
    float llacc = 0.f;
#pragma unroll
    for (int r = 0; r < 4; r++) {
        const int row = rbase + r;
        float w0 = W[(size_t)row * 30 + l15];
        float w1 = c2ok ? W[(size_t)row * 30 + 16 + l15] : -1e30f;
        float m = fmaxf(w0, w1);
#pragma unroll
        for (int mm = 1; mm < 16; mm <<= 1) m = fmaxf(m, __shfl_xor(m, mm, 64));
        float e0 = __expf(w0 - m);
        float e1 = c2ok ? __expf(w1 - m) : 0.f;
        float s = e0 + e1;
#pragma unroll
        for (int mm = 1; mm < 16; mm <<= 1) s += __shfl_xor(s, mm, 64);
        float inv = 1.0f / s;
        float p0 = e0 * inv, p1 = e1 * inv;
        float Sn = S[row], Sn2 = Sn * Sn;
        float F0 = -0.5f * (acc[0][r] - 2.0f * Sn * acc[2][r] + Sn2 * d0);
        float F1 = -0.5f * (acc[1][r] - 2.0f * Sn * acc[3][r] + Sn2 * d1);
        float lp = p0 * F0 + (c2ok ? p1 * F1 : 0.f);
#pragma unroll
        for (int mm = 1; mm < 16; mm <<= 1) lp += __shfl_xor(lp, mm, 64);
        llacc += lp;

        out[2 + (size_t)row * 30 + l15] = p0;
        float lg0 = __logf(p0 + 1e-8f);
        Pb[(size_t)row * 32 + l15] = (unsigned short)f2bf_u(p0);
        Lb[(size_t)row * 32 + l15] = (unsigned short)f2bf_u(lg0);
        if (c2ok) {
            out[2 + (size_t)row * 30 + 16 + l15] = p1;
            float lg1 = __logf(p1 + 1e-8f);
            Pb[(size_t)row * 32 + 16 + l15] = (unsigned short)f2bf_u(p1);
            Lb[(size_t)row * 32 + 16 + l15] = (unsigned short)f2bf_u(lg1);
        } else {
            Pb[(size_t)row * 32 + 16 + l15] = 0;
            Lb[(size_t)row * 32 + 16 + l15] = 0;
        }
        if (l15 >= 14)                xl[(size_t)row * 8 + (l15 - 14)] = acc[3][r] + bl[l15 - 14];
        else if (l15 < 6)             xl[(size_t)row * 8 + (l15 + 2)]  = acc[4][r] + bl[l15 + 2];
        if (l15 >= 6 && l15 < 14)     xr[(size_t)row * 8 + (l15 - 6)]  = acc[4][r] + br[l15 - 6];
    }
    llacc += __shfl_xor(llacc, 16, 64);
    llacc += __shfl_xor(llacc, 32, 64);
    if (l == 0) atomicAdd(&out[0], llacc * (1.0f / N_CELLS));
}

// ---------------------------------------------------------------------------
// K2: SINGLE edge pass, 4 lanes/edge (coalesced gathers), (p, p*dot) pair
// atomics into NREP replicated same-line slots by dst.
// ---------------------------------------------------------------------------
__global__ __launch_bounds__(256) void edge_pass(
    const int* __restrict__ ei, const float* __restrict__ xl,
    const float* __restrict__ xr, const float* __restrict__ att,
    const unsigned short* __restrict__ Pb, const unsigned short* __restrict__ Lb,
    float* __restrict__ dn4) {
    const int t = threadIdx.x;
    const int g = t >> 2;                     // group in block [0,64)
    const int j = t & 3;
    const int e = blockIdx.x * 64 + g;        // E = 12500*64 exactly
    const int src = ei[e];
    const int dst = ei[E_EDGES + e];

    float2 lv = *(const float2*)&xl[(size_t)src * 8 + j * 2];
    float2 rv = *(const float2*)&xr[(size_t)dst * 8 + j * 2];
    float2 av = *(const float2*)&att[j * 2];
    float ev = lrelu02(lv.x + rv.x) * av.x + lrelu02(lv.y + rv.y) * av.y;
    ev += __shfl_xor(ev, 1, 64);
    ev += __shfl_xor(ev, 2, 64);
    float p = __expf(ev);                     // |ev| ~ O(10): no max-subtraction

    int4 a = *(const int4*)&Pb[(size_t)src * 32 + j * 8];
    int4 b = *(const int4*)&Lb[(size_t)dst * 32 + j * 8];
    float dot = dp4(a, b);
    dot += __shfl_xor(dot, 1, 64);
    dot += __shfl_xor(dot, 2, 64);

    float* base = &dn4[((size_t)(blockIdx.x & (NREP - 1)) * N_CELLS + dst) * 2];
    if (j == 0)      atomicAdd(base, p);
    else if (j == 1) atomicAdd(base + 1, p * dot);
}

// ---------------------------------------------------------------------------
// K3: finalize — fold replicas, ce = -sum numer/denom / N
// ---------------------------------------------------------------------------
__global__ __launch_bounds__(256) void finalize_kernel(const float* __restrict__ dn4,
                                                       float* __restrict__ out) {
    const int t = threadIdx.x;
    const int i = blockIdx.x * 256 + t;
    float c = 0.f;
    if (i < N_CELLS) {
        float d  = (dn4[(size_t)i * 2]     + dn4[((size_t)N_CELLS + i) * 2]) +
                   (dn4[((size_t)2 * N_CELLS + i) * 2] + dn4[((size_t)3 * N_CELLS + i) * 2]);
        float nm = (dn4[(size_t)i * 2 + 1] + dn4[((size_t)N_CELLS + i) * 2 + 1]) +
                   (dn4[((size_t)2 * N_CELLS + i) * 2 + 1] + dn4[((size_t)3 * N_CELLS + i) * 2 + 1]);
        c = nm / (d + 1e-16f);
    }
#pragma unroll
    for (int m = 1; m < 64; m <<= 1) c += __shfl_xor(c, m, 64);
    __shared__ float wsum[4];
    if ((t & 63) == 0) wsum[t >> 6] = c;
    __syncthreads();
    if (t == 0)
        atomicAdd(&out[1], -(wsum[0] + wsum[1] + wsum[2] + wsum[3]) * (1.0f / N_CELLS));
}

// ---------------------------------------------------------------------------
// launch
// ---------------------------------------------------------------------------
extern "C" void kernel_launch(void* const* d_in, const int* in_sizes, int n_in,
                              void* d_out, int out_size, void* d_ws, size_t ws_size,
                              hipStream_t stream) {
    const float* X   = (const float*)d_in[0];
    const float* Mu  = (const float*)d_in[1];
    const float* Var = (const float*)d_in[2];
    const int*   ei  = (const int*)d_in[3];
    const float* W   = (const float*)d_in[4];
    const float* S   = (const float*)d_in[5];
    const float* Wl  = (const float*)d_in[6];
    const float* bl  = (const float*)d_in[7];
    const float* Wr  = (const float*)d_in[8];
    const float* br  = (const float*)d_in[9];
    const float* att = (const float*)d_in[10];

    float* out = (float*)d_out;

    // ws layout (float offsets)
    float* wsf = (float*)d_ws;
    unsigned short* CoefT  = (unsigned short*)wsf;             // 160 KB = 40960 fl
    float* Dvec            = wsf + 40960;                      // 32
    unsigned short* Pb     = (unsigned short*)(wsf + 40992);   // N*32 us = 800000 fl
    unsigned short* Lb     = (unsigned short*)(wsf + 840992);  // N*32 us
    float* xl              = wsf + 1640992;                    // N*8
    float* xr              = wsf + 2040992;                    // N*8
    float* dn4             = wsf + 2440992;                    // NREP*N*2 = 400000

    prep_kernel<<<400, 256, 0, stream>>>(Mu, Var, Wl, Wr, CoefT, Dvec, dn4, out);
    main_rows_kernel<<<N_CELLS / 16, 256, 0, stream>>>(
        X, W, S, bl, br, CoefT, Dvec, out, Pb, Lb, xl, xr);
    edge_pass<<<E_EDGES / 64, 256, 0, stream>>>(ei, xl, xr, att, Pb, Lb, dn4);
    finalize_kernel<<<(N_CELLS + 255) / 256, 256, 0, stream>>>(dn4, out);
}